// Round 1
// baseline (1867.646 us; speedup 1.0000x reference)
//
#include <hip/hip_runtime.h>
#include <hip/hip_bf16.h>

// NodeModel: edge MLP (Linear 192->128 + BN + ReLU) -> scatter-mean ->
//            node MLP (Linear 256->256 + BN + ReLU) -> Linear 256->128 + ReLU
//
// Design:
//  - All GEMMs via v_mfma_f32_16x16x32_bf16 (inputs RNE-rounded to bf16, f32 acc).
//  - BatchNorm needs column stats BEFORE the nonlinearity -> two GEMM passes
//    (stats pass discards y; apply pass recomputes y). Recompute is cheap at
//    MFMA rate and avoids an 819MB h-tensor in scratch.
//  - BN absorbs the linear bias: bn(y+b) = (y - mu_raw)*sc + be, so b1/b2 are
//    never touched. bl applied in the final kernel.
//  - s (segment sum) accumulates via f32 atomics directly in d_out (25.6MB,
//    exactly out_size). d_out is then rewritten in place: s -> z(bf16) -> out.
//    In-place safety: each tile's rows are read fully before being written,
//    enforced by per-tile __syncthreads() (all waves of a block share a tile;
//    different blocks own disjoint tiles).
//  - ws usage: 1536 floats of stats + 50000 floats of cnt = ~206KB.

#define NN 50000
#define NE 1600000
#define FN 128
#define FE 64
#define LDIM 128
#define E2 256
#define FOUT 128
#define EPSBN 1e-5f
#define WS_CNT 1536

typedef __bf16 bf16x8 __attribute__((ext_vector_type(8)));
typedef unsigned short u16x8 __attribute__((ext_vector_type(8)));
typedef float f32x4 __attribute__((ext_vector_type(4)));

__device__ __forceinline__ unsigned short f2bf(float f) {
  return __builtin_bit_cast(unsigned short, __float2bfloat16(f));
}
__device__ __forceinline__ bf16x8 packbf8(f32x4 a, f32x4 b) {
  u16x8 t;
  t[0] = f2bf(a[0]); t[1] = f2bf(a[1]); t[2] = f2bf(a[2]); t[3] = f2bf(a[3]);
  t[4] = f2bf(b[0]); t[5] = f2bf(b[1]); t[6] = f2bf(b[2]); t[7] = f2bf(b[3]);
  return __builtin_bit_cast(bf16x8, t);
}

// ---------------- edge GEMM pass 1: column sum/sumsq of y1 = A@W1, + cnt ----
__global__ __launch_bounds__(256) void k_edge_stats(
    const float* __restrict__ x, const int* __restrict__ ei,
    const float* __restrict__ ea, const float* __restrict__ W1,
    float* __restrict__ ws)
{
  const int wid = threadIdx.x >> 6;       // 4 waves, each owns 32 cols
  const int lane = threadIdx.x & 63;
  const int lr = lane & 15, kg = lane >> 4;
  const int cbase = wid * 32;

  bf16x8 B0[6], B1[6];
  #pragma unroll
  for (int kk = 0; kk < 6; ++kk) {
    u16x8 t0, t1;
    #pragma unroll
    for (int i = 0; i < 8; ++i) {
      int k = kk * 32 + kg * 8 + i;
      t0[i] = f2bf(W1[k * LDIM + cbase + lr]);
      t1[i] = f2bf(W1[k * LDIM + cbase + 16 + lr]);
    }
    B0[kk] = __builtin_bit_cast(bf16x8, t0);
    B1[kk] = __builtin_bit_cast(bf16x8, t1);
  }

  float ps0 = 0.f, pq0 = 0.f, ps1 = 0.f, pq1 = 0.f;
  float* cnt = ws + WS_CNT;

  for (int tile = blockIdx.x; tile < NE / 16; tile += gridDim.x) {
    const int e = tile * 16 + lr;
    const int r = ei[e];
    const float* xr = x + r * FN;
    const float* er = ea + e * FE;
    bf16x8 A[6];
    #pragma unroll
    for (int kk = 0; kk < 4; ++kk) {
      f32x4 p0 = *(const f32x4*)(xr + kk * 32 + kg * 8);
      f32x4 p1 = *(const f32x4*)(xr + kk * 32 + kg * 8 + 4);
      A[kk] = packbf8(p0, p1);
    }
    #pragma unroll
    for (int kk = 0; kk < 2; ++kk) {
      f32x4 p0 = *(const f32x4*)(er + kk * 32 + kg * 8);
      f32x4 p1 = *(const f32x4*)(er + kk * 32 + kg * 8 + 4);
      A[4 + kk] = packbf8(p0, p1);
    }
    f32x4 a0 = {0.f, 0.f, 0.f, 0.f}, a1 = {0.f, 0.f, 0.f, 0.f};
    #pragma unroll
    for (int kk = 0; kk < 6; ++kk) {
      a0 = __builtin_amdgcn_mfma_f32_16x16x32_bf16(A[kk], B0[kk], a0, 0, 0, 0);
      a1 = __builtin_amdgcn_mfma_f32_16x16x32_bf16(A[kk], B1[kk], a1, 0, 0, 0);
    }
    #pragma unroll
    for (int j = 0; j < 4; ++j) {
      ps0 += a0[j]; pq0 += a0[j] * a0[j];
      ps1 += a1[j]; pq1 += a1[j] * a1[j];
    }
    if (wid == 0 && lane < 16)
      atomicAdd(&cnt[ei[NE + tile * 16 + lane]], 1.0f);
  }
  ps0 += __shfl_xor(ps0, 16); ps0 += __shfl_xor(ps0, 32);
  pq0 += __shfl_xor(pq0, 16); pq0 += __shfl_xor(pq0, 32);
  ps1 += __shfl_xor(ps1, 16); ps1 += __shfl_xor(ps1, 32);
  pq1 += __shfl_xor(pq1, 16); pq1 += __shfl_xor(pq1, 32);
  if (lane < 16) {
    atomicAdd(&ws[cbase + lr], ps0);
    atomicAdd(&ws[128 + cbase + lr], pq0);
    atomicAdd(&ws[cbase + 16 + lr], ps1);
    atomicAdd(&ws[128 + cbase + 16 + lr], pq1);
  }
}

__global__ void k_fin1(const float* __restrict__ g, const float* __restrict__ be,
                       float* __restrict__ ws)
{
  const int c = threadIdx.x;  // 128
  const float mu = ws[c] * (1.0f / NE);
  float var = ws[128 + c] * (1.0f / NE) - mu * mu;
  var = fmaxf(var, 0.0f);
  const float sc = g[c] / sqrtf(var + EPSBN);
  ws[256 + c] = sc;
  ws[384 + c] = be[c] - mu * sc;
}

// ---------------- edge GEMM pass 2: recompute, BN+ReLU, scatter-add ---------
__global__ __launch_bounds__(256) void k_edge_scatter(
    const float* __restrict__ x, const int* __restrict__ ei,
    const float* __restrict__ ea, const float* __restrict__ W1,
    const float* __restrict__ ws, float* __restrict__ sOut)
{
  const int wid = threadIdx.x >> 6;
  const int lane = threadIdx.x & 63;
  const int lr = lane & 15, kg = lane >> 4;
  const int cbase = wid * 32;

  bf16x8 B0[6], B1[6];
  #pragma unroll
  for (int kk = 0; kk < 6; ++kk) {
    u16x8 t0, t1;
    #pragma unroll
    for (int i = 0; i < 8; ++i) {
      int k = kk * 32 + kg * 8 + i;
      t0[i] = f2bf(W1[k * LDIM + cbase + lr]);
      t1[i] = f2bf(W1[k * LDIM + cbase + 16 + lr]);
    }
    B0[kk] = __builtin_bit_cast(bf16x8, t0);
    B1[kk] = __builtin_bit_cast(bf16x8, t1);
  }
  const float sc0 = ws[256 + cbase + lr],      sh0 = ws[384 + cbase + lr];
  const float sc1 = ws[256 + cbase + 16 + lr], sh1 = ws[384 + cbase + 16 + lr];

  for (int tile = blockIdx.x; tile < NE / 16; tile += gridDim.x) {
    const int e = tile * 16 + lr;
    const int r = ei[e];
    const float* xr = x + r * FN;
    const float* er = ea + e * FE;
    bf16x8 A[6];
    #pragma unroll
    for (int kk = 0; kk < 4; ++kk) {
      f32x4 p0 = *(const f32x4*)(xr + kk * 32 + kg * 8);
      f32x4 p1 = *(const f32x4*)(xr + kk * 32 + kg * 8 + 4);
      A[kk] = packbf8(p0, p1);
    }
    #pragma unroll
    for (int kk = 0; kk < 2; ++kk) {
      f32x4 p0 = *(const f32x4*)(er + kk * 32 + kg * 8);
      f32x4 p1 = *(const f32x4*)(er + kk * 32 + kg * 8 + 4);
      A[4 + kk] = packbf8(p0, p1);
    }
    f32x4 a0 = {0.f, 0.f, 0.f, 0.f}, a1 = {0.f, 0.f, 0.f, 0.f};
    #pragma unroll
    for (int kk = 0; kk < 6; ++kk) {
      a0 = __builtin_amdgcn_mfma_f32_16x16x32_bf16(A[kk], B0[kk], a0, 0, 0, 0);
      a1 = __builtin_amdgcn_mfma_f32_16x16x32_bf16(A[kk], B1[kk], a1, 0, 0, 0);
    }
    #pragma unroll
    for (int j = 0; j < 4; ++j) {
      const int d = ei[NE + tile * 16 + kg * 4 + j];
      const float v0 = fmaxf(a0[j] * sc0 + sh0, 0.f);
      const float v1 = fmaxf(a1[j] * sc1 + sh1, 0.f);
      atomicAdd(&sOut[d * LDIM + cbase + lr], v0);
      atomicAdd(&sOut[d * LDIM + cbase + 16 + lr], v1);
    }
  }
}

// ---------------- node GEMM2 pass 1: column stats of y2 = [x|agg]@W2 --------
__global__ __launch_bounds__(512) void k_node_stats(
    const float* __restrict__ x, const float* __restrict__ sAgg,
    const float* __restrict__ W2, float* __restrict__ ws)
{
  const int wid = threadIdx.x >> 6;       // 8 waves x 32 cols = 256 cols
  const int lane = threadIdx.x & 63;
  const int lr = lane & 15, kg = lane >> 4;
  const int cbase = wid * 32;

  bf16x8 B0[8], B1[8];
  #pragma unroll
  for (int kk = 0; kk < 8; ++kk) {
    u16x8 t0, t1;
    #pragma unroll
    for (int i = 0; i < 8; ++i) {
      int k = kk * 32 + kg * 8 + i;
      t0[i] = f2bf(W2[k * E2 + cbase + lr]);
      t1[i] = f2bf(W2[k * E2 + cbase + 16 + lr]);
    }
    B0[kk] = __builtin_bit_cast(bf16x8, t0);
    B1[kk] = __builtin_bit_cast(bf16x8, t1);
  }
  const float* cnt = ws + WS_CNT;
  float ps0 = 0.f, pq0 = 0.f, ps1 = 0.f, pq1 = 0.f;

  for (int tile = blockIdx.x; tile < NN / 16; tile += gridDim.x) {
    const int n = tile * 16 + lr;
    const float cv = cnt[n];
    const float inv = cv > 0.f ? 1.f / cv : 0.f;
    bf16x8 A[8];
    #pragma unroll
    for (int kk = 0; kk < 4; ++kk) {
      f32x4 p0 = *(const f32x4*)(x + n * FN + kk * 32 + kg * 8);
      f32x4 p1 = *(const f32x4*)(x + n * FN + kk * 32 + kg * 8 + 4);
      A[kk] = packbf8(p0, p1);
    }
    #pragma unroll
    for (int kk = 0; kk < 4; ++kk) {
      f32x4 p0 = *(const f32x4*)(sAgg + n * LDIM + kk * 32 + kg * 8);
      f32x4 p1 = *(const f32x4*)(sAgg + n * LDIM + kk * 32 + kg * 8 + 4);
      p0 = p0 * inv; p1 = p1 * inv;
      A[4 + kk] = packbf8(p0, p1);
    }
    f32x4 a0 = {0.f, 0.f, 0.f, 0.f}, a1 = {0.f, 0.f, 0.f, 0.f};
    #pragma unroll
    for (int kk = 0; kk < 8; ++kk) {
      a0 = __builtin_amdgcn_mfma_f32_16x16x32_bf16(A[kk], B0[kk], a0, 0, 0, 0);
      a1 = __builtin_amdgcn_mfma_f32_16x16x32_bf16(A[kk], B1[kk], a1, 0, 0, 0);
    }
    #pragma unroll
    for (int j = 0; j < 4; ++j) {
      ps0 += a0[j]; pq0 += a0[j] * a0[j];
      ps1 += a1[j]; pq1 += a1[j] * a1[j];
    }
  }
  ps0 += __shfl_xor(ps0, 16); ps0 += __shfl_xor(ps0, 32);
  pq0 += __shfl_xor(pq0, 16); pq0 += __shfl_xor(pq0, 32);
  ps1 += __shfl_xor(ps1, 16); ps1 += __shfl_xor(ps1, 32);
  pq1 += __shfl_xor(pq1, 16); pq1 += __shfl_xor(pq1, 32);
  if (lane < 16) {
    atomicAdd(&ws[512 + cbase + lr], ps0);
    atomicAdd(&ws[768 + cbase + lr], pq0);
    atomicAdd(&ws[512 + cbase + 16 + lr], ps1);
    atomicAdd(&ws[768 + cbase + 16 + lr], pq1);
  }
}

__global__ void k_fin2(const float* __restrict__ g, const float* __restrict__ be,
                       float* __restrict__ ws)
{
  const int c = threadIdx.x;  // 256
  const float mu = ws[512 + c] * (1.0f / NN);
  float var = ws[768 + c] * (1.0f / NN) - mu * mu;
  var = fmaxf(var, 0.0f);
  const float sc = g[c] / sqrtf(var + EPSBN);
  ws[1024 + c] = sc;
  ws[1280 + c] = be[c] - mu * sc;
}

// ---------------- node GEMM2 pass 2: BN+ReLU, write z (bf16) over s in d_out
__global__ __launch_bounds__(512) void k_node_z(
    const float* __restrict__ x, const float* __restrict__ W2,
    const float* __restrict__ ws, float* dout /* in: s (f32), out: z (bf16) */)
{
  const int wid = threadIdx.x >> 6;
  const int lane = threadIdx.x & 63;
  const int lr = lane & 15, kg = lane >> 4;
  const int cbase = wid * 32;

  bf16x8 B0[8], B1[8];
  #pragma unroll
  for (int kk = 0; kk < 8; ++kk) {
    u16x8 t0, t1;
    #pragma unroll
    for (int i = 0; i < 8; ++i) {
      int k = kk * 32 + kg * 8 + i;
      t0[i] = f2bf(W2[k * E2 + cbase + lr]);
      t1[i] = f2bf(W2[k * E2 + cbase + 16 + lr]);
    }
    B0[kk] = __builtin_bit_cast(bf16x8, t0);
    B1[kk] = __builtin_bit_cast(bf16x8, t1);
  }
  const float* cnt = ws + WS_CNT;
  const float sc0 = ws[1024 + cbase + lr],      sh0 = ws[1280 + cbase + lr];
  const float sc1 = ws[1024 + cbase + 16 + lr], sh1 = ws[1280 + cbase + 16 + lr];

  for (int tile = blockIdx.x; tile < NN / 16; tile += gridDim.x) {
    const int n = tile * 16 + lr;
    const float cv = cnt[n];
    const float inv = cv > 0.f ? 1.f / cv : 0.f;
    bf16x8 A[8];
    #pragma unroll
    for (int kk = 0; kk < 4; ++kk) {
      f32x4 p0 = *(const f32x4*)(x + n * FN + kk * 32 + kg * 8);
      f32x4 p1 = *(const f32x4*)(x + n * FN + kk * 32 + kg * 8 + 4);
      A[kk] = packbf8(p0, p1);
    }
    #pragma unroll
    for (int kk = 0; kk < 4; ++kk) {
      f32x4 p0 = *(const f32x4*)(dout + n * LDIM + kk * 32 + kg * 8);
      f32x4 p1 = *(const f32x4*)(dout + n * LDIM + kk * 32 + kg * 8 + 4);
      p0 = p0 * inv; p1 = p1 * inv;
      A[4 + kk] = packbf8(p0, p1);
    }
    f32x4 a0 = {0.f, 0.f, 0.f, 0.f}, a1 = {0.f, 0.f, 0.f, 0.f};
    #pragma unroll
    for (int kk = 0; kk < 8; ++kk) {
      a0 = __builtin_amdgcn_mfma_f32_16x16x32_bf16(A[kk], B0[kk], a0, 0, 0, 0);
      a1 = __builtin_amdgcn_mfma_f32_16x16x32_bf16(A[kk], B1[kk], a1, 0, 0, 0);
    }
    __syncthreads();  // all waves finished reading this tile's s rows
    unsigned short* zp = (unsigned short*)dout;
    #pragma unroll
    for (int j = 0; j < 4; ++j) {
      const int n2 = tile * 16 + kg * 4 + j;
      zp[n2 * E2 + cbase + lr]      = f2bf(fmaxf(a0[j] * sc0 + sh0, 0.f));
      zp[n2 * E2 + cbase + 16 + lr] = f2bf(fmaxf(a1[j] * sc1 + sh1, 0.f));
    }
  }
}

// ---------------- final: out = relu(z @ Wl + bl), in place over z -----------
__global__ __launch_bounds__(256) void k_out(
    const float* __restrict__ Wl, const float* __restrict__ bl,
    float* dout /* in: z (bf16 rows, 512B), out: f32 rows */)
{
  const int wid = threadIdx.x >> 6;       // 4 waves x 32 cols = 128 cols
  const int lane = threadIdx.x & 63;
  const int lr = lane & 15, kg = lane >> 4;
  const int cbase = wid * 32;

  bf16x8 B0[8], B1[8];
  #pragma unroll
  for (int kk = 0; kk < 8; ++kk) {
    u16x8 t0, t1;
    #pragma unroll
    for (int i = 0; i < 8; ++i) {
      int k = kk * 32 + kg * 8 + i;
      t0[i] = f2bf(Wl[k * FOUT + cbase + lr]);
      t1[i] = f2bf(Wl[k * FOUT + cbase + 16 + lr]);
    }
    B0[kk] = __builtin_bit_cast(bf16x8, t0);
    B1[kk] = __builtin_bit_cast(bf16x8, t1);
  }
  const float bl0 = bl[cbase + lr], bl1 = bl[cbase + 16 + lr];

  for (int tile = blockIdx.x; tile < NN / 16; tile += gridDim.x) {
    const int n = tile * 16 + lr;
    const char* zrow = (const char*)dout + (size_t)n * 512;
    bf16x8 A[8];
    #pragma unroll
    for (int kk = 0; kk < 8; ++kk) {
      f32x4 raw = *(const f32x4*)(zrow + kk * 64 + kg * 16);
      A[kk] = __builtin_bit_cast(bf16x8, raw);
    }
    f32x4 a0 = {0.f, 0.f, 0.f, 0.f}, a1 = {0.f, 0.f, 0.f, 0.f};
    #pragma unroll
    for (int kk = 0; kk < 8; ++kk) {
      a0 = __builtin_amdgcn_mfma_f32_16x16x32_bf16(A[kk], B0[kk], a0, 0, 0, 0);
      a1 = __builtin_amdgcn_mfma_f32_16x16x32_bf16(A[kk], B1[kk], a1, 0, 0, 0);
    }
    __syncthreads();  // all waves finished reading this tile's z rows
    #pragma unroll
    for (int j = 0; j < 4; ++j) {
      const int n2 = tile * 16 + kg * 4 + j;
      dout[n2 * FN + cbase + lr]      = fmaxf(a0[j] + bl0, 0.f);
      dout[n2 * FN + cbase + 16 + lr] = fmaxf(a1[j] + bl1, 0.f);
    }
  }
}

extern "C" void kernel_launch(void* const* d_in, const int* in_sizes, int n_in,
                              void* d_out, int out_size, void* d_ws, size_t ws_size,
                              hipStream_t stream)
{
  const float* x   = (const float*)d_in[0];
  const int*   ei  = (const int*)d_in[1];
  const float* ea  = (const float*)d_in[2];
  const float* W1  = (const float*)d_in[5];
  const float* g1  = (const float*)d_in[7];
  const float* be1 = (const float*)d_in[8];
  const float* W2  = (const float*)d_in[9];
  const float* g2  = (const float*)d_in[11];
  const float* be2 = (const float*)d_in[12];
  const float* Wl  = (const float*)d_in[13];
  const float* bl  = (const float*)d_in[14];
  float* out = (float*)d_out;
  float* ws  = (float*)d_ws;

  hipMemsetAsync(ws, 0, (WS_CNT + NN) * sizeof(float), stream);
  hipMemsetAsync(out, 0, (size_t)NN * FN * sizeof(float), stream);

  k_edge_stats<<<4096, 256, 0, stream>>>(x, ei, ea, W1, ws);
  k_fin1<<<1, 128, 0, stream>>>(g1, be1, ws);
  k_edge_scatter<<<4096, 256, 0, stream>>>(x, ei, ea, W1, ws, out);
  k_node_stats<<<512, 512, 0, stream>>>(x, out, W2, ws);
  k_fin2<<<1, 256, 0, stream>>>(g2, be2, ws);
  k_node_z<<<512, 512, 0, stream>>>(x, W2, ws, out);
  k_out<<<1024, 256, 0, stream>>>(Wl, bl, out);
}